// Round 9
// baseline (202.685 us; speedup 1.0000x reference)
//
#include <hip/hip_runtime.h>
#include <hip/hip_bf16.h>
#include <math.h>

// Problem constants: B=4, T=4096, C=1024, H=64
#define Bn 4
#define Tn 4096
#define Cn 1024
#define Hn 64

typedef __bf16 bf16_t;
typedef __bf16 bf16x8 __attribute__((ext_vector_type(8)));
typedef float f32x4 __attribute__((ext_vector_type(4)));

// bf16-element workspace offsets
#define WT_OFF 0
#define Q_OFF   196608
#define K_OFF   (Q_OFF + 1048576)
#define VT_OFF  (K_OFF + 1048576)
#define PART_OFF (VT_OFF + 1048576)     // 3,342,336: Opart bf16 region
// attn tiling: 128-row Q-tiles (32/batch), 64-col units, <=8 splits/tile
#define NTILE 32
#define NSMX 8
#define SLOTS (Bn * NTILE * NSMX)       // slots x 8192 el (16 KB bf16 each)

// ---------------------------------------------------------------------------
// Kernel 0: WT[n][k] = W_sel[k][n&63] bf16 (scale*log2e folded into Wq rows).
// ---------------------------------------------------------------------------
__global__ void wt_kernel(const float* __restrict__ Wq, const float* __restrict__ Wk,
                          const float* __restrict__ Wv, bf16_t* __restrict__ WT) {
    int idx = blockIdx.x * 256 + threadIdx.x;   // idx = n*1024 + k
    int n = idx >> 10;
    int k = idx & 1023;
    const float* W = (n < 64) ? Wq : (n < 128) ? Wk : Wv;
    float s = (n < 64) ? 0.1803368801111204f : 1.0f;   // H^-0.5 * log2(e)
    WT[idx] = (bf16_t)(W[(size_t)k * 64 + (n & 63)] * s);
}

// ---------------------------------------------------------------------------
// Kernel 1: QKV projection v4 — occupancy over footprint. WT staged in 256-K
// chunks ([48][264] = 25.3 KB -> 4 blocks/CU, 16 waves/CU). Grid 1024 =
// 256 M-groups (64 rows) x 4 N-tiles (48 cols), swizzled so an M-group's
// 4 N-tiles share an XCD (x row fetched once into that L2). Next WT chunk
// register-prefetched during compute; 2 barriers per chunk.
// ---------------------------------------------------------------------------
__launch_bounds__(256, 4)
__global__ void proj_kernel(const float* __restrict__ x, const bf16_t* __restrict__ WT,
                            bf16_t* __restrict__ q, bf16_t* __restrict__ kmat,
                            bf16_t* __restrict__ vt) {
    __shared__ bf16_t wsld[48][264];

    const int tid  = threadIdx.x;
    const int wave = tid >> 6;
    const int lane = tid & 63;
    const int l15  = lane & 15;
    const int quad = lane >> 4;
    const int blk  = blockIdx.x;
    const int mg = ((blk >> 5) << 3) | (blk & 7);   // 0..255, 4 N-tiles same XCD
    const int j2 = (blk >> 3) & 3;                  // N-tile 0..3
    const int n0 = j2 * 48;

    const int mrow = mg * 64 + wave * 16;           // wave's 16 rows
    const float* xf = x + (size_t)(mrow + l15) * Cn + quad * 8;

    f32x4 acc[3];
#pragma unroll
    for (int nn = 0; nn < 3; ++nn) acc[nn] = (f32x4){0.f, 0.f, 0.f, 0.f};

    uint4 wr[6];
    // WT chunk: 48 rows x 256 K = 1536 8-el chunks over 256 thr -> 6 each
#define LOADW(k0)                                                               \
    {                                                                           \
        _Pragma("unroll")                                                       \
        for (int i = 0; i < 6; ++i) {                                           \
            int id = i * 256 + tid;  int n = id >> 5;  int ck = id & 31;        \
            wr[i] = *(const uint4*)(WT + (size_t)(n0 + n) * Cn + (k0) + ck * 8);\
        }                                                                       \
    }
#define STOREW()                                                                \
    {                                                                           \
        _Pragma("unroll")                                                       \
        for (int i = 0; i < 6; ++i) {                                           \
            int id = i * 256 + tid;  int n = id >> 5;  int ck = id & 31;        \
            *(uint4*)&wsld[n][ck * 8] = wr[i];                                  \
        }                                                                       \
    }

    LOADW(0);
    STOREW();
    __syncthreads();

    for (int c = 0; c < 4; ++c) {
        if (c < 3) LOADW((c + 1) * 256);      // prefetch next chunk into regs
#pragma unroll
        for (int kk = 0; kk < 256; kk += 32) {
            float4 v0 = *(const float4*)(xf + c * 256 + kk);
            float4 v1 = *(const float4*)(xf + c * 256 + kk + 4);
            bf16x8 a0;
            a0[0] = (bf16_t)v0.x; a0[1] = (bf16_t)v0.y; a0[2] = (bf16_t)v0.z; a0[3] = (bf16_t)v0.w;
            a0[4] = (bf16_t)v1.x; a0[5] = (bf16_t)v1.y; a0[6] = (bf16_t)v1.z; a0[7] = (bf16_t)v1.w;
#pragma unroll
            for (int nn = 0; nn < 3; ++nn) {
                bf16x8 b = *(const bf16x8*)&wsld[nn * 16 + l15][kk + quad * 8];
                acc[nn] = __builtin_amdgcn_mfma_f32_16x16x32_bf16(a0, b, acc[nn], 0, 0, 0);
            }
        }
        __syncthreads();
        if (c < 3) { STOREW(); __syncthreads(); }
    }
#undef LOADW
#undef STOREW

    // ---- epilogue: C/D layout col=lane&15, row=quad*4+reg ----
#pragma unroll
    for (int nn = 0; nn < 3; ++nn) {
        int n = n0 + nn * 16 + l15;
#pragma unroll
        for (int r = 0; r < 4; ++r) {
            int row = mrow + quad * 4 + r;
            float v = acc[nn][r];
            if (n < 64) {
                q[(size_t)row * Hn + n] = (bf16_t)v;
            } else if (n < 128) {
                kmat[(size_t)row * Hn + (n - 64)] = (bf16_t)v;
            } else {
                int b  = row >> 12;
                int tr = row & (Tn - 1);
                vt[((size_t)b * Hn + (n - 128)) * Tn + tr] = (bf16_t)v;
            }
        }
    }
}

// ---------------------------------------------------------------------------
// Kernel 2: split-KV causal flash attention, 512 thr (8 waves), 128-row
// Q-tiles. Tile t: 2t+2 units, ns(t)=min(8,ceil((t+1)/2)) splits round-robin
// -> 200 blocks/batch = 800 total, each 2..8 units. 36 KB LDS. No running
// max. Coalesced bf16 partials in register order [slot][tid][16].
// ---------------------------------------------------------------------------
__launch_bounds__(512, 8)
__global__ void attn_part(const bf16_t* __restrict__ q, const bf16_t* __restrict__ kmat,
                          const bf16_t* __restrict__ vt, bf16_t* __restrict__ Opart,
                          float* __restrict__ lpart) {
    __shared__ bf16_t kbuf[64][72];
    __shared__ bf16_t vbuf[64][72];
    __shared__ bf16_t p_lds[8][16][72];

    const int tid  = threadIdx.x;
    const int wave = tid >> 6;
    const int lane = tid & 63;
    const int l15  = lane & 15;
    const int quad = lane >> 4;

    // ---- decode (b, tile t, split s); ns(t)=min(8,ceil((t+1)/2)) ----
    const int blk = blockIdx.x;
    const int b   = blk & 3;
    const int w   = blk >> 2;           // 0..199
    int t, s, ns;
    if (w < 56) {
        // pairs (t=2a, 2a+1), ns=a+1 each; cum(a) = a(a+1)
        int a = (int)((sqrtf(1.0f + 4.0f * (float)w) - 1.0f) * 0.5f);
        while ((a + 1) * (a + 2) <= w) ++a;
        while (a * (a + 1) > w) --a;
        int rem = w - a * (a + 1);
        ns = a + 1;
        if (rem >= ns) { t = 2 * a + 1; s = rem - ns; }
        else           { t = 2 * a;     s = rem; }
    } else {
        int v = w - 56;
        t = 14 + (v >> 3);
        s = v & 7;
        ns = 8;
    }
    const int n_u = 2 * t + 2;              // KV units for this tile
    const int cnt = (n_u - 1 - s) / ns + 1; // units for this split
    const int q0  = t * 128;

    size_t qbase = ((size_t)b * Tn + q0 + wave * 16 + l15) * Hn;
    bf16x8 qf0 = *(const bf16x8*)(q + qbase + quad * 8);
    bf16x8 qf1 = *(const bf16x8*)(q + qbase + 32 + quad * 8);

    const bf16_t* kb = kmat + (size_t)b * Tn * Hn;
    const bf16_t* vb = vt + (size_t)b * Hn * Tn;

    f32x4 acc_o[4];
#pragma unroll
    for (int i = 0; i < 4; ++i) acc_o[i] = (f32x4){0.f, 0.f, 0.f, 0.f};
    float lsum[4] = {0.f, 0.f, 0.f, 0.f};

    const int srow = tid >> 3;   // staging: 64 rows x 8 chunks over 512 thr
    const int sc8  = tid & 7;

    uint4 kr, vr;
#define LOAD_UNIT(uu)                                                           \
    {                                                                           \
        const int s0l = (uu) * 64;                                              \
        kr = *(const uint4*)(kb + (size_t)(s0l + srow) * Hn + sc8 * 8);         \
        vr = *(const uint4*)(vb + (size_t)srow * Tn + s0l + sc8 * 8);           \
    }

    LOAD_UNIT(s);
    int u = s;
    for (int i = 0; i < cnt; ++i) {
        __syncthreads();
        *(uint4*)&kbuf[srow][sc8 * 8] = kr;
        *(uint4*)&vbuf[srow][sc8 * 8] = vr;
        __syncthreads();
        const int un = u + ns;
        if (i + 1 < cnt) LOAD_UNIT(un);    // in flight across compute

        // ---- S = Q K^T (scale pre-folded into q) ----
        f32x4 accs[4];
#pragma unroll
        for (int ts = 0; ts < 4; ++ts) accs[ts] = (f32x4){0.f, 0.f, 0.f, 0.f};
#pragma unroll
        for (int ts = 0; ts < 4; ++ts) {
            bf16x8 kf0 = *(const bf16x8*)&kbuf[ts * 16 + l15][quad * 8];
            bf16x8 kf1 = *(const bf16x8*)&kbuf[ts * 16 + l15][32 + quad * 8];
            accs[ts] = __builtin_amdgcn_mfma_f32_16x16x32_bf16(qf0, kf0, accs[ts], 0, 0, 0);
            accs[ts] = __builtin_amdgcn_mfma_f32_16x16x32_bf16(qf1, kf1, accs[ts], 0, 0, 0);
        }
        // ---- causal mask: only when unit reaches wave's rows ----
        const int s0 = u * 64;
        const int rowb = q0 + wave * 16 + quad * 4;
        if (s0 + 63 > q0 + wave * 16) {        // wave-uniform
#pragma unroll
            for (int ts = 0; ts < 4; ++ts) {
                int col = s0 + ts * 16 + l15;
#pragma unroll
                for (int r = 0; r < 4; ++r)
                    accs[ts][r] = (col > rowb + r) ? -128.f : accs[ts][r];
            }
        }
        // ---- P = exp2(S); per-lane l; P -> wave-private LDS (C->A) ----
#pragma unroll
        for (int ts = 0; ts < 4; ++ts) {
#pragma unroll
            for (int r = 0; r < 4; ++r) {
                float p = exp2f(accs[ts][r]);
                lsum[r] += p;
                p_lds[wave][quad * 4 + r][ts * 16 + l15] = (bf16_t)p;
            }
        }
        // ---- O += P V ----
#pragma unroll
        for (int kk = 0; kk < 64; kk += 32) {
            bf16x8 pf = *(const bf16x8*)&p_lds[wave][l15][kk + quad * 8];
#pragma unroll
            for (int t2 = 0; t2 < 4; ++t2) {
                bf16x8 vf = *(const bf16x8*)&vbuf[t2 * 16 + l15][kk + quad * 8];
                acc_o[t2] = __builtin_amdgcn_mfma_f32_16x16x32_bf16(pf, vf, acc_o[t2], 0, 0, 0);
            }
        }
        u = un;
    }
#undef LOAD_UNIT

    // ---- one deferred cross-lane l reduction ----
#pragma unroll
    for (int r = 0; r < 4; ++r) {
        float v = lsum[r];
        v += __shfl_xor(v, 1);
        v += __shfl_xor(v, 2);
        v += __shfl_xor(v, 4);
        v += __shfl_xor(v, 8);
        lsum[r] = v;
    }
    // ---- coalesced partials: [slot][tid][16] bf16, register order ----
    const int slot = (b * NTILE + t) * NSMX + s;
    bf16x8 o0, o1;
#pragma unroll
    for (int e = 0; e < 8; ++e) { o0[e] = (bf16_t)acc_o[e >> 2][e & 3]; o1[e] = (bf16_t)acc_o[2 + (e >> 2)][e & 3]; }
    bf16_t* op = Opart + (size_t)slot * 8192 + (size_t)tid * 16;
    *(bf16x8*)op = o0;
    *(bf16x8*)(op + 8) = o1;
    if (l15 == 0) {
#pragma unroll
        for (int r = 0; r < 4; ++r)
            lpart[(size_t)slot * 128 + wave * 16 + quad * 4 + r] = lsum[r];
    }
}

// ---------------------------------------------------------------------------
// Kernel 3: combine partials + normalize. Grid (32, B), 512 thr mirroring
// attn lane structure. ns(t) must match attn_part.
// ---------------------------------------------------------------------------
__launch_bounds__(512)
__global__ void combine_kernel(const bf16_t* __restrict__ Opart, const float* __restrict__ lpart,
                               float* __restrict__ out) {
    const int t = blockIdx.x;
    const int b = blockIdx.y;
    int ns = (t + 2) >> 1;  if (ns > 8) ns = 8;
    const int tid  = threadIdx.x;
    const int wave = tid >> 6;
    const int lane = tid & 63;
    const int l15  = lane & 15;
    const int quad = lane >> 4;

    float o[16];
#pragma unroll
    for (int i = 0; i < 16; ++i) o[i] = 0.f;
    float L[4] = {0.f, 0.f, 0.f, 0.f};

    for (int s = 0; s < ns; ++s) {
        const int slot = (b * NTILE + t) * NSMX + s;
        const bf16_t* op = Opart + (size_t)slot * 8192 + (size_t)tid * 16;
        bf16x8 v0 = *(const bf16x8*)op;
        bf16x8 v1 = *(const bf16x8*)(op + 8);
#pragma unroll
        for (int i = 0; i < 8; ++i) { o[i] += (float)v0[i]; o[8 + i] += (float)v1[i]; }
#pragma unroll
        for (int r = 0; r < 4; ++r)
            L[r] += lpart[(size_t)slot * 128 + wave * 16 + quad * 4 + r];
    }
    float inv[4];
#pragma unroll
    for (int r = 0; r < 4; ++r) inv[r] = 1.f / L[r];
#pragma unroll
    for (int t2 = 0; t2 < 4; ++t2) {
#pragma unroll
        for (int r = 0; r < 4; ++r) {
            size_t row = (size_t)b * Tn + t * 128 + wave * 16 + quad * 4 + r;
            out[row * Hn + t2 * 16 + l15] = o[t2 * 4 + r] * inv[r];
        }
    }
}

// ---------------------------------------------------------------------------
extern "C" void kernel_launch(void* const* d_in, const int* in_sizes, int n_in,
                              void* d_out, int out_size, void* d_ws, size_t ws_size,
                              hipStream_t stream) {
    const float* x  = (const float*)d_in[0];
    const float* Wq = (const float*)d_in[1];
    const float* Wk = (const float*)d_in[2];
    const float* Wv = (const float*)d_in[3];
    float* out = (float*)d_out;

    bf16_t* wsb = (bf16_t*)d_ws;
    bf16_t* WT = wsb + WT_OFF;
    bf16_t* qb = wsb + Q_OFF;
    bf16_t* kb = wsb + K_OFF;
    bf16_t* vt = wsb + VT_OFF;
    bf16_t* Opart = wsb + PART_OFF;
    float*  lpart = (float*)(Opart + (size_t)SLOTS * 8192);

    // blocks/batch = sum_t min(8, ceil((t+1)/2)) = 200
    const int per_batch = 200;

    wt_kernel<<<dim3(192 * 1024 / 256), dim3(256), 0, stream>>>(Wq, Wk, Wv, WT);
    proj_kernel<<<dim3(1024), dim3(256), 0, stream>>>(x, WT, qb, kb, vt);
    attn_part<<<dim3(per_batch * Bn), dim3(512), 0, stream>>>(qb, kb, vt, Opart, lpart);
    combine_kernel<<<dim3(NTILE, Bn), dim3(512), 0, stream>>>(Opart, lpart, out);
}